// Round 6
// baseline (1994.092 us; speedup 1.0000x reference)
//
#include <hip/hip_runtime.h>
#include <hip/hip_bf16.h>
#include <math.h>

typedef __attribute__((ext_vector_type(8))) short short8;
typedef __attribute__((ext_vector_type(4))) float f32x4;
typedef __attribute__((ext_vector_type(4))) unsigned short us4;

__device__ __forceinline__ float b2f(unsigned short u) {
    union { unsigned int i; float f; } v; v.i = ((unsigned int)u) << 16; return v.f;
}
__device__ __forceinline__ unsigned short f2b(float f) {
    __hip_bfloat16 h = __float2bfloat16(f);
    return *reinterpret_cast<unsigned short*>(&h);
}

// ---------------------------------------------------------------------------
// K0: h_grid (128,128ch,64x64) fp32 -> ht (128,4096px,128ch) bf16
// Coalesced writes: ushort4 per lane (512 B per wave-store).
// rep=4 for rocprof visibility (idempotent).
// ---------------------------------------------------------------------------
#define TREP 4
__global__ __launch_bounds__(256) void transpose_h(const float* __restrict__ hg,
                                                   unsigned short* __restrict__ ht) {
    __shared__ float t[128][65];                 // [ch][px], pad+1: in-phase conflict-free
    int bid = blockIdx.x;                        // 8192 = 128 img * 64 px-blocks
    int n = bid >> 6, pb = bid & 63;
    int tid = threadIdx.x;
    const float* src = hg + (size_t)n * 128 * 4096 + pb * 64;
    int j = tid & 63, i0 = tid >> 6;
#pragma unroll 1
    for (int rep = 0; rep < TREP; ++rep) {
#pragma unroll
        for (int ii = 0; ii < 32; ++ii) {
            int ch = ii * 4 + i0;
            t[ch][j] = src[(size_t)ch * 4096 + j];
        }
        __syncthreads();
#pragma unroll
        for (int it = 0; it < 8; ++it) {
            int idx = tid + it * 256;
            int px = idx >> 5, cq = idx & 31;    // 4 channels per lane
            us4 o;
#pragma unroll
            for (int r = 0; r < 4; ++r) o[r] = f2b(t[cq * 4 + r][px]);
            *(us4*)&ht[((size_t)n * 4096 + pb * 64 + px) * 128 + cq * 4] = o;
        }
        __syncthreads();
    }
}

// ---------------------------------------------------------------------------
// K1: weights -> transposed bf16 + padded W2 strip
// ---------------------------------------------------------------------------
__global__ void prep_weights(const float* __restrict__ W0, const float* __restrict__ W1,
                             const float* __restrict__ W2,
                             unsigned short* __restrict__ w0t, unsigned short* __restrict__ w1t,
                             unsigned short* __restrict__ w2p) {
    int i = blockIdx.x * 256 + threadIdx.x;
    const int total0 = 128 * 384, total1 = 128 * 128, total2 = 16 * 128;
    for (int idx = i; idx < total0; idx += gridDim.x * 256) {
        int j = idx / 384, k = idx - j * 384;
        w0t[idx] = f2b(W0[k * 128 + j]);
    }
    for (int idx = i; idx < total1; idx += gridDim.x * 256) {
        int j = idx >> 7, k = idx & 127;
        w1t[idx] = f2b(W1[k * 128 + j]);
    }
    for (int idx = i; idx < total2; idx += gridDim.x * 256) {
        int r = idx >> 7, k = idx & 127;
        w2p[idx] = (r < 2) ? f2b(W2[k * 2 + r]) : (unsigned short)0;
    }
}

// ---------------------------------------------------------------------------
// K2: fused, templated for ablation. MODE: 0=full, 1=no-gather, 2=no-trig.
// MINW: __launch_bounds__ min waves/EU. rep=2 for rocprof visibility.
// ---------------------------------------------------------------------------
#define MFMA_BF16 __builtin_amdgcn_mfma_f32_16x16x32_bf16
#define FREP 2

template<int MODE, int MINW>
__global__ __launch_bounds__(1024, MINW) void fused_decoder(
    const unsigned short* __restrict__ ht,
    const float* __restrict__ xs, const float* __restrict__ ys,
    const float* __restrict__ Bm,
    const unsigned short* __restrict__ w0t, const float* __restrict__ b0,
    const unsigned short* __restrict__ w1t, const float* __restrict__ b1,
    const unsigned short* __restrict__ w2p, const float* __restrict__ b2,
    float* __restrict__ out)
{
    __shared__ unsigned short smem[81920];           // 160 KB exactly
    unsigned short* w0s = smem;                      // 96 KB swizzled
    int tid = threadIdx.x, lane = tid & 63, w = tid >> 6;
    int lr = lane & 15, lg = lane >> 4;
    char* hb = (char*)(smem + 49152 + w * 2048);     // per-wave 16x128 bf16

#pragma unroll 1
    for (int rep = 0; rep < FREP; ++rep) {
        // ---- stage W0 into LDS with XOR swizzle
        {
            const short8* src = (const short8*)w0t;
#pragma unroll
            for (int it = 0; it < 6; ++it) {
                int c = tid + it * 1024;
                int row = c / 48;
                int wb = (c - row * 48) * 16;
                short8 v = src[c];
                *(short8*)((char*)w0s + row * 768 + (wb ^ ((row & 7) << 4))) = v;
            }
        }
        __syncthreads();

        int bid = blockIdx.x;
        int x = bid & 7, s = bid >> 3;
        int n = x * 16 + (s >> 3);
        int pt = s & 7;
        int gp0 = n * 2048 + pt * 256 + w * 16;
        int gp = gp0 + lr;

        float xc = xs[gp], yc = ys[gp];
        float px = xc * 63.f, py = yc * 63.f;
        float x0f = fminf(fmaxf(floorf(px), 0.f), 63.f);
        float y0f = fminf(fmaxf(floorf(py), 0.f), 63.f);
        float wx = px - x0f, wy = py - y0f;
        float ivx = 1.f - wx, ivy = 1.f - wy;
        int xi0 = (int)x0f, yi0 = (int)y0f;
        int xi1 = min(xi0 + 1, 63), yi1 = min(yi0 + 1, 63);
        const char* base = (const char*)ht + ((size_t)n << 20) + lg * 16;
        int o00 = (yi0 * 64 + xi0) * 256, o01 = (yi0 * 64 + xi1) * 256;
        int o10 = (yi1 * 64 + xi0) * 256, o11 = (yi1 * 64 + xi1) * 256;

        // ================= layer 0 =================
        f32x4 acc[8];
#pragma unroll
        for (int nj = 0; nj < 8; ++nj) {
            float bv = b0[nj * 16 + lr];
            acc[nj] = (f32x4){bv, bv, bv, bv};
        }

#pragma unroll
        for (int s4 = 0; s4 < 4; ++s4) {
            short8 c00, c01, c10, c11;
            if (MODE != 1) {
                c00 = *(const short8*)(base + o00 + s4 * 64);
                c01 = *(const short8*)(base + o01 + s4 * 64);
                c10 = *(const short8*)(base + o10 + s4 * 64);
                c11 = *(const short8*)(base + o11 + s4 * 64);
            }

            short8 asn, acs;
            if (MODE != 2) {
                int f0 = s4 * 32 + lg * 8;
                f32x4 B0a = *(const f32x4*)&Bm[f0];
                f32x4 B0b = *(const f32x4*)&Bm[f0 + 4];
                f32x4 B1a = *(const f32x4*)&Bm[128 + f0];
                f32x4 B1b = *(const f32x4*)&Bm[128 + f0 + 4];
                float t_[8];
#pragma unroll
                for (int j = 0; j < 4; ++j) {
                    t_[j]     = xc * B0a[j] + yc * B1a[j];
                    t_[4 + j] = xc * B0b[j] + yc * B1b[j];
                }
#pragma unroll
                for (int j = 0; j < 8; ++j) {
                    float tf = t_[j] - floorf(t_[j]);
                    float sv, cv;
                    asm("v_sin_f32 %0, %1" : "=v"(sv) : "v"(tf));
                    asm("v_cos_f32 %0, %1" : "=v"(cv) : "v"(tf));
                    asn[j] = (short)f2b(sv);
                    acs[j] = (short)f2b(cv);
                }
            } else {
                unsigned short uv = f2b(xc);        // not compile-time foldable
#pragma unroll
                for (int j = 0; j < 8; ++j) { asn[j] = (short)uv; acs[j] = (short)uv; }
            }
            int kbs = (4 + s4) * 64 + lg * 16, kbc = (8 + s4) * 64 + lg * 16;
#pragma unroll
            for (int nj = 0; nj < 8; ++nj) {
                int row = nj * 16 + lr;
                short8 bs = *(const short8*)((const char*)w0s + row * 768 + (kbs ^ ((lr & 7) << 4)));
                acc[nj] = MFMA_BF16(asn, bs, acc[nj], 0, 0, 0);
            }
#pragma unroll
            for (int nj = 0; nj < 8; ++nj) {
                int row = nj * 16 + lr;
                short8 bc = *(const short8*)((const char*)w0s + row * 768 + (kbc ^ ((lr & 7) << 4)));
                acc[nj] = MFMA_BF16(acs, bc, acc[nj], 0, 0, 0);
            }

            short8 a;
            if (MODE != 1) {
#pragma unroll
                for (int j = 0; j < 8; ++j) {
                    float top = b2f((unsigned short)c00[j]) * ivx + b2f((unsigned short)c01[j]) * wx;
                    float bot = b2f((unsigned short)c10[j]) * ivx + b2f((unsigned short)c11[j]) * wx;
                    a[j] = (short)f2b(top * ivy + bot * wy);
                }
            } else {
                a = acs;                              // keep MFMA count identical
            }
            int kba = s4 * 64 + lg * 16;
#pragma unroll
            for (int nj = 0; nj < 8; ++nj) {
                int row = nj * 16 + lr;
                short8 b = *(const short8*)((const char*)w0s + row * 768 + (kba ^ ((lr & 7) << 4)));
                acc[nj] = MFMA_BF16(a, b, acc[nj], 0, 0, 0);
            }
        }

        // ================= layer 1 =================
#pragma unroll
        for (int nj = 0; nj < 8; ++nj)
#pragma unroll
            for (int r = 0; r < 4; ++r) {
                int row = lg * 4 + r;
                int cb2 = (nj * 16 + lr) * 2;
                *(unsigned short*)(hb + row * 256 + (cb2 ^ ((row & 7) << 4))) =
                    f2b(fmaxf(acc[nj][r], 0.f));
            }
        asm volatile("s_waitcnt lgkmcnt(0)" ::: "memory");
        short8 a1[4];
#pragma unroll
        for (int ks = 0; ks < 4; ++ks)
            a1[ks] = *(const short8*)(hb + lr * 256 + ((ks * 64 + lg * 16) ^ ((lr & 7) << 4)));
        asm volatile("s_waitcnt lgkmcnt(0)" ::: "memory");

#pragma unroll
        for (int nj = 0; nj < 8; ++nj) {
            float bv = b1[nj * 16 + lr];
            acc[nj] = (f32x4){bv, bv, bv, bv};
        }
#pragma unroll
        for (int ks = 0; ks < 4; ++ks)
#pragma unroll
            for (int nj = 0; nj < 8; ++nj) {
                short8 b = *(const short8*)&w1t[(nj * 16 + lr) * 128 + ks * 32 + lg * 8];
                acc[nj] = MFMA_BF16(a1[ks], b, acc[nj], 0, 0, 0);
            }

        // ================= layer 2 =================
#pragma unroll
        for (int nj = 0; nj < 8; ++nj)
#pragma unroll
            for (int r = 0; r < 4; ++r) {
                int row = lg * 4 + r;
                int cb2 = (nj * 16 + lr) * 2;
                *(unsigned short*)(hb + row * 256 + (cb2 ^ ((row & 7) << 4))) =
                    f2b(fmaxf(acc[nj][r], 0.f));
            }
        asm volatile("s_waitcnt lgkmcnt(0)" ::: "memory");
        float bb2 = (lr < 2) ? b2[lr] : 0.f;
        f32x4 acc2 = (f32x4){bb2, bb2, bb2, bb2};
#pragma unroll
        for (int ks = 0; ks < 4; ++ks) {
            short8 a2 = *(const short8*)(hb + lr * 256 + ((ks * 64 + lg * 16) ^ ((lr & 7) << 4)));
            short8 bz = *(const short8*)&w2p[lr * 128 + ks * 32 + lg * 8];
            acc2 = MFMA_BF16(a2, bz, acc2, 0, 0, 0);
        }
        if (lr < 2) {
#pragma unroll
            for (int r = 0; r < 4; ++r) {
                int gpo = gp0 + lg * 4 + r;
                float v = acc2[r];
                if (lr == 0) {
                    out[gpo * 2] = v;
                } else {
                    float sp = (v > 20.f) ? v : log1pf(expf(v));
                    out[gpo * 2 + 1] = sp + 0.01f;
                }
            }
        }
        __syncthreads();
    }
}

// ---------------------------------------------------------------------------
extern "C" void kernel_launch(void* const* d_in, const int* in_sizes, int n_in,
                              void* d_out, int out_size, void* d_ws, size_t ws_size,
                              hipStream_t stream) {
    const float* h_grid = (const float*)d_in[0];
    const float* xs = (const float*)d_in[1];
    const float* ys = (const float*)d_in[2];
    const float* Bm = (const float*)d_in[3];
    const float* W0 = (const float*)d_in[4];
    const float* b0 = (const float*)d_in[5];
    const float* W1 = (const float*)d_in[6];
    const float* b1 = (const float*)d_in[7];
    const float* W2 = (const float*)d_in[8];
    const float* b2 = (const float*)d_in[9];
    float* out = (float*)d_out;

    unsigned short* ht  = (unsigned short*)d_ws;
    unsigned short* w0t = (unsigned short*)((char*)d_ws + 134217728ull);
    unsigned short* w1t = w0t + 128 * 384;
    unsigned short* w2p = w1t + 128 * 128;

    transpose_h<<<dim3(8192), dim3(256), 0, stream>>>(h_grid, ht);
    prep_weights<<<dim3(64), dim3(256), 0, stream>>>(W0, W1, W2, w0t, w1t, w2p);
    // ablations first (outputs overwritten), correct full kernel LAST defines d_out
    fused_decoder<1, 4><<<dim3(1024), dim3(1024), 0, stream>>>(ht, xs, ys, Bm, w0t, b0, w1t, b1, w2p, b2, out);
    fused_decoder<2, 4><<<dim3(1024), dim3(1024), 0, stream>>>(ht, xs, ys, Bm, w0t, b0, w1t, b1, w2p, b2, out);
    fused_decoder<0, 4><<<dim3(1024), dim3(1024), 0, stream>>>(ht, xs, ys, Bm, w0t, b0, w1t, b1, w2p, b2, out);
    fused_decoder<0, 2><<<dim3(1024), dim3(1024), 0, stream>>>(ht, xs, ys, Bm, w0t, b0, w1t, b1, w2p, b2, out);
}

// Round 7
// 198.804 us; speedup vs baseline: 10.0304x; 10.0304x over previous
//
#include <hip/hip_runtime.h>
#include <hip/hip_bf16.h>
#include <math.h>

typedef __attribute__((ext_vector_type(8))) short short8;
typedef __attribute__((ext_vector_type(4))) float f32x4;
typedef __attribute__((ext_vector_type(4))) unsigned short us4;

__device__ __forceinline__ float b2f(unsigned short u) {
    union { unsigned int i; float f; } v; v.i = ((unsigned int)u) << 16; return v.f;
}
__device__ __forceinline__ unsigned short f2b(float f) {
    __hip_bfloat16 h = __float2bfloat16(f);
    return *reinterpret_cast<unsigned short*>(&h);
}

// ---------------------------------------------------------------------------
// K0: h_grid (128,128ch,64x64) fp32 -> ht (128,4096px,128ch) bf16
// Coalesced: ushort4 per lane on the store side.
// ---------------------------------------------------------------------------
__global__ __launch_bounds__(256) void transpose_h(const float* __restrict__ hg,
                                                   unsigned short* __restrict__ ht) {
    __shared__ float t[128][65];
    int bid = blockIdx.x;                        // 8192 = 128 img * 64 px-blocks
    int n = bid >> 6, pb = bid & 63;
    int tid = threadIdx.x;
    const float* src = hg + (size_t)n * 128 * 4096 + pb * 64;
    int j = tid & 63, i0 = tid >> 6;
#pragma unroll
    for (int ii = 0; ii < 32; ++ii) {
        int ch = ii * 4 + i0;
        t[ch][j] = src[(size_t)ch * 4096 + j];
    }
    __syncthreads();
#pragma unroll
    for (int it = 0; it < 8; ++it) {
        int idx = tid + it * 256;
        int px = idx >> 5, cq = idx & 31;        // 4 channels per lane
        us4 o;
#pragma unroll
        for (int r = 0; r < 4; ++r) o[r] = f2b(t[cq * 4 + r][px]);
        *(us4*)&ht[((size_t)n * 4096 + pb * 64 + px) * 128 + cq * 4] = o;
    }
}

// ---------------------------------------------------------------------------
// K1: weights -> transposed bf16 + padded W2 strip
// ---------------------------------------------------------------------------
__global__ void prep_weights(const float* __restrict__ W0, const float* __restrict__ W1,
                             const float* __restrict__ W2,
                             unsigned short* __restrict__ w0t, unsigned short* __restrict__ w1t,
                             unsigned short* __restrict__ w2p) {
    int i = blockIdx.x * 256 + threadIdx.x;
    const int total0 = 128 * 384, total1 = 128 * 128, total2 = 16 * 128;
    for (int idx = i; idx < total0; idx += gridDim.x * 256) {
        int j = idx / 384, k = idx - j * 384;
        w0t[idx] = f2b(W0[k * 128 + j]);
    }
    for (int idx = i; idx < total1; idx += gridDim.x * 256) {
        int j = idx >> 7, k = idx & 127;
        w1t[idx] = f2b(W1[k * 128 + j]);
    }
    for (int idx = i; idx < total2; idx += gridDim.x * 256) {
        int r = idx >> 7, k = idx & 127;
        w2p[idx] = (r < 2) ? f2b(W2[k * 2 + r]) : (unsigned short)0;
    }
}

// ---------------------------------------------------------------------------
// K2: fused. 512 thr (8 waves), 32 pts/wave. W0 in LDS with 784B row pitch
// (conflict-free b128 reads). Rolled x2 slice loop, 2-set corner prefetch.
// ---------------------------------------------------------------------------
#define W0P 784     // 768 data + 16 pad; 196 dw = 4 mod 32 -> conflict-free
#define HBP 272     // 256 data + 16 pad; 16B aligned rows
#define MFMA_BF16 __builtin_amdgcn_mfma_f32_16x16x32_bf16

__global__ __launch_bounds__(512, 2) void fused_decoder(
    const unsigned short* __restrict__ ht,
    const float* __restrict__ xs, const float* __restrict__ ys,
    const float* __restrict__ Bm,
    const unsigned short* __restrict__ w0t, const float* __restrict__ b0,
    const unsigned short* __restrict__ w1t, const float* __restrict__ b1,
    const unsigned short* __restrict__ w2p, const float* __restrict__ b2,
    float* __restrict__ out)
{
    __shared__ char smem[128 * W0P + 8 * 16 * HBP];   // 100352 + 34816 = 135168
    char* w0s = smem;
    int tid = threadIdx.x, lane = tid & 63, w = tid >> 6;
    int lr = lane & 15, lg = lane >> 4;
    char* hb = smem + 128 * W0P + w * 16 * HBP;

    // ---- stage W0 into LDS, 784B pitch (6144 16B chunks, 12/thread)
    {
        const short8* src = (const short8*)w0t;
#pragma unroll 1
        for (int it = 0; it < 12; ++it) {
            int c = tid + it * 512;
            int row = c / 48, cc = c - row * 48;
            *(short8*)(w0s + row * W0P + cc * 16) = src[c];
        }
    }
    __syncthreads();

    // block -> (xcd, slot): concurrent blocks per XCD cover ~4 images (L2-fit)
    int bid = blockIdx.x;                 // 1024 = 8 xcd * 128
    int x = bid & 7, s = bid >> 3;
    int n = x * 16 + (s >> 3);            // image 0..127
    int pt = s & 7;                       // 256-pt tile within image
    int gp0 = n * 2048 + pt * 256 + w * 32;

    // ---- per-m coords
    float xm[2], ym[2], wxv[2], wyv[2];
    int o00[2], o01[2], o10[2], o11[2];
#pragma unroll
    for (int m = 0; m < 2; ++m) {
        int gp = gp0 + m * 16 + lr;
        float xc = xs[gp], yc = ys[gp];
        xm[m] = xc; ym[m] = yc;
        float px = xc * 63.f, py = yc * 63.f;
        float x0f = fminf(fmaxf(floorf(px), 0.f), 63.f);
        float y0f = fminf(fmaxf(floorf(py), 0.f), 63.f);
        wxv[m] = px - x0f; wyv[m] = py - y0f;
        int xi0 = (int)x0f, yi0 = (int)y0f;
        int xi1 = min(xi0 + 1, 63), yi1 = min(yi0 + 1, 63);
        o00[m] = (yi0 * 64 + xi0) * 256;
        o01[m] = (yi0 * 64 + xi1) * 256;
        o10[m] = (yi1 * 64 + xi0) * 256;
        o11[m] = (yi1 * 64 + xi1) * 256;
    }
    const char* base = (const char*)ht + ((size_t)n << 20) + lg * 16;

    // ================= layer 0 =================
    f32x4 acc[2][8];
#pragma unroll
    for (int nj = 0; nj < 8; ++nj) {
        float bv = b0[nj * 16 + lr];
        acc[0][nj] = (f32x4){bv, bv, bv, bv};
        acc[1][nj] = acc[0][nj];
    }

    short8 A00[2], A01[2], A10[2], A11[2];   // corner set A (even slices)
    short8 B00[2], B01[2], B10[2], B11[2];   // corner set B (odd slices)
#pragma unroll
    for (int m = 0; m < 2; ++m) {
        A00[m] = *(const short8*)(base + o00[m]);
        A01[m] = *(const short8*)(base + o01[m]);
        A10[m] = *(const short8*)(base + o10[m]);
        A11[m] = *(const short8*)(base + o11[m]);
        B00[m] = *(const short8*)(base + o00[m] + 64);
        B01[m] = *(const short8*)(base + o01[m] + 64);
        B10[m] = *(const short8*)(base + o10[m] + 64);
        B11[m] = *(const short8*)(base + o11[m] + 64);
    }

#pragma unroll 1
    for (int s2 = 0; s2 < 2; ++s2) {
        // =========== half 1: slice q0 = 2*s2 (uses set A) ===========
        {
            int q = 2 * s2;
            short8 asn[2], acs[2];
#pragma unroll
            for (int m = 0; m < 2; ++m) {
                int f0 = q * 32 + lg * 8;
                f32x4 B0a = *(const f32x4*)&Bm[f0];
                f32x4 B0b = *(const f32x4*)&Bm[f0 + 4];
                f32x4 B1a = *(const f32x4*)&Bm[128 + f0];
                f32x4 B1b = *(const f32x4*)&Bm[128 + f0 + 4];
                float t_[8];
#pragma unroll
                for (int j = 0; j < 4; ++j) {
                    t_[j]     = xm[m] * B0a[j] + ym[m] * B1a[j];
                    t_[4 + j] = xm[m] * B0b[j] + ym[m] * B1b[j];
                }
#pragma unroll
                for (int j = 0; j < 8; ++j) {
                    float tf = t_[j] - floorf(t_[j]);
                    float sv, cv;
                    asm("v_sin_f32 %0, %1" : "=v"(sv) : "v"(tf));
                    asm("v_cos_f32 %0, %1" : "=v"(cv) : "v"(tf));
                    asn[m][j] = (short)f2b(sv);
                    acs[m][j] = (short)f2b(cv);
                }
            }
#pragma unroll
            for (int nj = 0; nj < 8; ++nj) {
                short8 bs = *(const short8*)(w0s + (nj * 16 + lr) * W0P + (4 + q) * 64 + lg * 16);
                acc[0][nj] = MFMA_BF16(asn[0], bs, acc[0][nj], 0, 0, 0);
                acc[1][nj] = MFMA_BF16(asn[1], bs, acc[1][nj], 0, 0, 0);
            }
#pragma unroll
            for (int nj = 0; nj < 8; ++nj) {
                short8 bc = *(const short8*)(w0s + (nj * 16 + lr) * W0P + (8 + q) * 64 + lg * 16);
                acc[0][nj] = MFMA_BF16(acs[0], bc, acc[0][nj], 0, 0, 0);
                acc[1][nj] = MFMA_BF16(acs[1], bc, acc[1][nj], 0, 0, 0);
            }
            short8 a[2];
#pragma unroll
            for (int m = 0; m < 2; ++m) {
                float wx = wxv[m], wy = wyv[m];
                float ivx = 1.f - wx, ivy = 1.f - wy;
#pragma unroll
                for (int j = 0; j < 8; ++j) {
                    float top = b2f((unsigned short)A00[m][j]) * ivx + b2f((unsigned short)A01[m][j]) * wx;
                    float bot = b2f((unsigned short)A10[m][j]) * ivx + b2f((unsigned short)A11[m][j]) * wx;
                    a[m][j] = (short)f2b(top * ivy + bot * wy);
                }
            }
            if (s2 == 0) {                        // reload A with slice 2
#pragma unroll
                for (int m = 0; m < 2; ++m) {
                    A00[m] = *(const short8*)(base + o00[m] + 128);
                    A01[m] = *(const short8*)(base + o01[m] + 128);
                    A10[m] = *(const short8*)(base + o10[m] + 128);
                    A11[m] = *(const short8*)(base + o11[m] + 128);
                }
            }
#pragma unroll
            for (int nj = 0; nj < 8; ++nj) {
                short8 b = *(const short8*)(w0s + (nj * 16 + lr) * W0P + q * 64 + lg * 16);
                acc[0][nj] = MFMA_BF16(a[0], b, acc[0][nj], 0, 0, 0);
                acc[1][nj] = MFMA_BF16(a[1], b, acc[1][nj], 0, 0, 0);
            }
        }
        // =========== half 2: slice q1 = 2*s2+1 (uses set B) ===========
        {
            int q = 2 * s2 + 1;
            short8 asn[2], acs[2];
#pragma unroll
            for (int m = 0; m < 2; ++m) {
                int f0 = q * 32 + lg * 8;
                f32x4 B0a = *(const f32x4*)&Bm[f0];
                f32x4 B0b = *(const f32x4*)&Bm[f0 + 4];
                f32x4 B1a = *(const f32x4*)&Bm[128 + f0];
                f32x4 B1b = *(const f32x4*)&Bm[128 + f0 + 4];
                float t_[8];
#pragma unroll
                for (int j = 0; j < 4; ++j) {
                    t_[j]     = xm[m] * B0a[j] + ym[m] * B1a[j];
                    t_[4 + j] = xm[m] * B0b[j] + ym[m] * B1b[j];
                }
#pragma unroll
                for (int j = 0; j < 8; ++j) {
                    float tf = t_[j] - floorf(t_[j]);
                    float sv, cv;
                    asm("v_sin_f32 %0, %1" : "=v"(sv) : "v"(tf));
                    asm("v_cos_f32 %0, %1" : "=v"(cv) : "v"(tf));
                    asn[m][j] = (short)f2b(sv);
                    acs[m][j] = (short)f2b(cv);
                }
            }
#pragma unroll
            for (int nj = 0; nj < 8; ++nj) {
                short8 bs = *(const short8*)(w0s + (nj * 16 + lr) * W0P + (4 + q) * 64 + lg * 16);
                acc[0][nj] = MFMA_BF16(asn[0], bs, acc[0][nj], 0, 0, 0);
                acc[1][nj] = MFMA_BF16(asn[1], bs, acc[1][nj], 0, 0, 0);
            }
#pragma unroll
            for (int nj = 0; nj < 8; ++nj) {
                short8 bc = *(const short8*)(w0s + (nj * 16 + lr) * W0P + (8 + q) * 64 + lg * 16);
                acc[0][nj] = MFMA_BF16(acs[0], bc, acc[0][nj], 0, 0, 0);
                acc[1][nj] = MFMA_BF16(acs[1], bc, acc[1][nj], 0, 0, 0);
            }
            short8 a[2];
#pragma unroll
            for (int m = 0; m < 2; ++m) {
                float wx = wxv[m], wy = wyv[m];
                float ivx = 1.f - wx, ivy = 1.f - wy;
#pragma unroll
                for (int j = 0; j < 8; ++j) {
                    float top = b2f((unsigned short)B00[m][j]) * ivx + b2f((unsigned short)B01[m][j]) * wx;
                    float bot = b2f((unsigned short)B10[m][j]) * ivx + b2f((unsigned short)B11[m][j]) * wx;
                    a[m][j] = (short)f2b(top * ivy + bot * wy);
                }
            }
            if (s2 == 0) {                        // reload B with slice 3
#pragma unroll
                for (int m = 0; m < 2; ++m) {
                    B00[m] = *(const short8*)(base + o00[m] + 192);
                    B01[m] = *(const short8*)(base + o01[m] + 192);
                    B10[m] = *(const short8*)(base + o10[m] + 192);
                    B11[m] = *(const short8*)(base + o11[m] + 192);
                }
            }
#pragma unroll
            for (int nj = 0; nj < 8; ++nj) {
                short8 b = *(const short8*)(w0s + (nj * 16 + lr) * W0P + q * 64 + lg * 16);
                acc[0][nj] = MFMA_BF16(a[0], b, acc[0][nj], 0, 0, 0);
                acc[1][nj] = MFMA_BF16(a[1], b, acc[1][nj], 0, 0, 0);
            }
        }
    }

    // ================= layer 1: h0(32x128) @ W1(128x128) =================
    short8 a1[2][4];
#pragma unroll
    for (int m = 0; m < 2; ++m) {
#pragma unroll
        for (int nj = 0; nj < 8; ++nj)
#pragma unroll
            for (int r = 0; r < 4; ++r) {
                int row = lg * 4 + r;
                *(unsigned short*)(hb + row * HBP + (nj * 16 + lr) * 2) =
                    f2b(fmaxf(acc[m][nj][r], 0.f));
            }
        asm volatile("s_waitcnt lgkmcnt(0)" ::: "memory");
#pragma unroll
        for (int ks = 0; ks < 4; ++ks)
            a1[m][ks] = *(const short8*)(hb + lr * HBP + ks * 64 + lg * 16);
        asm volatile("s_waitcnt lgkmcnt(0)" ::: "memory");
    }
#pragma unroll
    for (int nj = 0; nj < 8; ++nj) {
        float bv = b1[nj * 16 + lr];
        acc[0][nj] = (f32x4){bv, bv, bv, bv};
        acc[1][nj] = acc[0][nj];
    }
#pragma unroll
    for (int ks = 0; ks < 4; ++ks)
#pragma unroll
        for (int nj = 0; nj < 8; ++nj) {
            short8 b = *(const short8*)&w1t[(nj * 16 + lr) * 128 + ks * 32 + lg * 8];
            acc[0][nj] = MFMA_BF16(a1[0][ks], b, acc[0][nj], 0, 0, 0);
            acc[1][nj] = MFMA_BF16(a1[1][ks], b, acc[1][nj], 0, 0, 0);
        }

    // ================= layer 2: h1 @ W2p(128x16, cols>=2 zero) ==============
    float bb2 = (lr < 2) ? b2[lr] : 0.f;
#pragma unroll
    for (int m = 0; m < 2; ++m) {
#pragma unroll
        for (int nj = 0; nj < 8; ++nj)
#pragma unroll
            for (int r = 0; r < 4; ++r) {
                int row = lg * 4 + r;
                *(unsigned short*)(hb + row * HBP + (nj * 16 + lr) * 2) =
                    f2b(fmaxf(acc[m][nj][r], 0.f));
            }
        asm volatile("s_waitcnt lgkmcnt(0)" ::: "memory");
        f32x4 acc2 = (f32x4){bb2, bb2, bb2, bb2};
#pragma unroll
        for (int ks = 0; ks < 4; ++ks) {
            short8 a2 = *(const short8*)(hb + lr * HBP + ks * 64 + lg * 16);
            short8 bz = *(const short8*)&w2p[lr * 128 + ks * 32 + lg * 8];
            acc2 = MFMA_BF16(a2, bz, acc2, 0, 0, 0);
        }
        asm volatile("s_waitcnt lgkmcnt(0)" ::: "memory");
        if (lr < 2) {
#pragma unroll
            for (int r = 0; r < 4; ++r) {
                int gpo = gp0 + m * 16 + lg * 4 + r;
                float v = acc2[r];
                if (lr == 0) {
                    out[gpo * 2] = v;
                } else {
                    float sp = (v > 20.f) ? v : log1pf(expf(v));
                    out[gpo * 2 + 1] = sp + 0.01f;
                }
            }
        }
    }
}

// ---------------------------------------------------------------------------
extern "C" void kernel_launch(void* const* d_in, const int* in_sizes, int n_in,
                              void* d_out, int out_size, void* d_ws, size_t ws_size,
                              hipStream_t stream) {
    const float* h_grid = (const float*)d_in[0];
    const float* xs = (const float*)d_in[1];
    const float* ys = (const float*)d_in[2];
    const float* Bm = (const float*)d_in[3];
    const float* W0 = (const float*)d_in[4];
    const float* b0 = (const float*)d_in[5];
    const float* W1 = (const float*)d_in[6];
    const float* b1 = (const float*)d_in[7];
    const float* W2 = (const float*)d_in[8];
    const float* b2 = (const float*)d_in[9];
    float* out = (float*)d_out;

    unsigned short* ht  = (unsigned short*)d_ws;
    unsigned short* w0t = (unsigned short*)((char*)d_ws + 134217728ull);
    unsigned short* w1t = w0t + 128 * 384;
    unsigned short* w2p = w1t + 128 * 128;

    transpose_h<<<dim3(8192), dim3(256), 0, stream>>>(h_grid, ht);
    prep_weights<<<dim3(64), dim3(256), 0, stream>>>(W0, W1, W2, w0t, w1t, w2p);
    fused_decoder<<<dim3(1024), dim3(512), 0, stream>>>(ht, xs, ys, Bm, w0t, b0, w1t, b1, w2p, b2, out);
}